// Round 5
// baseline (345.900 us; speedup 1.0000x reference)
//
#include <hip/hip_runtime.h>

// cdist(x1, x2) on MI355X: d[i][j] = sqrt(||x1_i||^2 + ||x2_j||^2 - 2*x1_i.x2_j)
// R5: persistent 2-phase pipelined GEMM + T2 LDS swizzle.
// R4 post-mortem: cdist ~122us ~= SUM of pipe rooflines (stores 43 + LDS 32 +
// MFMA 14 + epi-VALU 14 + L2 15) -> zero cross-pipe overlap from cohort
// lockstep (4096 identical blocks phase-synchronized; 2 barriers/K-step).
// Fixes:
//  - 512 persistent blocks (2/CU), 8 tiles each, flat 32-step double-buffered
//    pipeline (stage(next); compute(cur); sync) -> 1 barrier/step, no per-tile
//    prologue, epilogue issued mid-stream, blocks de-phase.
//  - T2 XOR swizzle: linear LDS dest (global_load_lds constraint, rule #21),
//    pre-swizzled per-lane GLOBAL source col ((lane&7)^(lane>>3)), swizzled
//    ds_read offsets -> 16-way bank conflict -> 2-way (free).
//  - consecutive tiles per block share bm -> A panel L2-hot.

typedef __bf16 v8bf __attribute__((ext_vector_type(8)));
typedef float v4f __attribute__((ext_vector_type(4)));

#define NROWS 8192
#define KDIM  256
#define TILE  128
#define BK    64
#define NTHREADS 512
#define NTILES  8
#define NSTEPS  (NTILES * 4)

typedef const __attribute__((address_space(1))) ushort* gas_ushort_p;
typedef __attribute__((address_space(3))) ushort* las_ushort_p;

__device__ __forceinline__ void async_load16(const ushort* g, ushort* l) {
    // global -> LDS direct DMA, 16B per lane. LDS dest is wave-uniform base +
    // lane*16 (linear); swizzle is applied on the GLOBAL source side.
    __builtin_amdgcn_global_load_lds((gas_ushort_p)g, (las_ushort_p)l, 16, 0, 0);
}

__device__ __forceinline__ ushort f2bf_rne(float f) {
    union { float f; unsigned u; } a; a.f = f;
    unsigned u = a.u + 0x7fffu + ((a.u >> 16) & 1u);  // round-to-nearest-even
    return (ushort)(u >> 16);
}

// One wave per row: load 256 floats as float4/lane, emit bf16 row + fp32 norm.
// Merged: first 2048 blocks process x1, rest x2.
__global__ __launch_bounds__(256) void cvt_norm_kernel(
    const float* __restrict__ x1, const float* __restrict__ x2,
    ushort* __restrict__ xb1, ushort* __restrict__ xb2,
    float* __restrict__ sq1, float* __restrict__ sq2) {
    const int half2 = NROWS / 4;  // 2048 blocks per input
    const float* x = (blockIdx.x < half2) ? x1 : x2;
    ushort* xb     = (blockIdx.x < half2) ? xb1 : xb2;
    float* sq      = (blockIdx.x < half2) ? sq1 : sq2;
    const int bb   = (blockIdx.x < half2) ? blockIdx.x : blockIdx.x - half2;

    const int wave = threadIdx.x >> 6;
    const int lane = threadIdx.x & 63;
    const int row  = bb * 4 + wave;
    const float4 v = ((const float4*)(x + (size_t)row * KDIM))[lane];
    float s = v.x * v.x + v.y * v.y + v.z * v.z + v.w * v.w;
#pragma unroll
    for (int off = 32; off; off >>= 1) s += __shfl_down(s, off);
    if (lane == 0) sq[row] = s;
    ushort4 o;
    o.x = f2bf_rne(v.x); o.y = f2bf_rne(v.y);
    o.z = f2bf_rne(v.z); o.w = f2bf_rne(v.w);
    ((ushort4*)(xb + (size_t)row * KDIM))[lane] = o;
}

__global__ __launch_bounds__(NTHREADS, 4) void cdist_mfma_kernel(
    const ushort* __restrict__ A,    // x1 bf16, [8192][256]
    const ushort* __restrict__ B,    // x2 bf16, [8192][256]
    const float* __restrict__ sq1,   // ||x1_i||^2
    const float* __restrict__ sq2,   // ||x2_j||^2
    float* __restrict__ out) {       // [8192][8192]
    __shared__ ushort As[2][TILE * BK];   // 2 x 16 KiB, double-buffered
    __shared__ ushort Bs[2][TILE * BK];   // 2 x 16 KiB  (total 64 KiB -> 2 blk/CU)

    // Persistent: 512 blocks, 8 tiles each. XCD chunking: chunk = 16(bm) x
    // 32(bn) tiles; block lb walks 8 tiles along bn at fixed bm (A L2-hot).
    const int bid = blockIdx.x;           // 0..511
    const int xcd = bid & 7;
    const int lb  = bid >> 3;             // 0..63 within XCD

    const int tid  = threadIdx.x;
    const int wave = tid >> 6;
    const int lane = tid & 63;
    const int wr = wave >> 2;             // 0..1 -> 64 rows
    const int wc = wave & 3;              // 0..3 -> 32 cols
    const int half = lane >> 4;           // 0..3
    const int mrow = lane & 15;           // fragment row/col within 16

    // staging lane layout: 8 lanes x 16B per row; global col16 XOR-swizzled so
    // the linear LDS write realizes LDS[row][c16 ^ (row&7)] = data[row][c16].
    const int lrow = lane >> 3;                   // 0..7 (== row & 7)
    const int lcol = ((lane & 7) ^ lrow) * 8;     // swizzle-compensated src col

    // swizzled LDS read offsets (bf16 elems): logical c16 = half (kk=0) or
    // half+4 (kk=32); physical = (c16 ^ (row&7))*8 with row&7 == mrow&7.
    const int swzlo = (half ^ (mrow & 7)) * 8;
    const int swzhi = ((half + 4) ^ (mrow & 7)) * 8;

    v4f acc[4][2];
#pragma unroll
    for (int i = 0; i < 4; ++i)
#pragma unroll
        for (int j = 0; j < 2; ++j) acc[i][j] = (v4f){0.f, 0.f, 0.f, 0.f};

    auto tileRows = [&](int t, int& rA, int& rB) {
        const int ct = lb + (t << 6);     // chunk-local tile id, 0..511
        rA = (((xcd & 3) << 4) | (ct & 15)) * TILE;
        rB = (((xcd >> 2) << 5) | (ct >> 4)) * TILE;
    };

    auto stage = [&](int buf, int rA, int rB, int kt) {
#pragma unroll
        for (int c = 0; c < 2; ++c) {
            const int rbase = wave * 16 + c * 8;   // 8 rows per wave-call
            async_load16(A + (size_t)(rA + rbase + lrow) * KDIM + kt + lcol,
                         &As[buf][rbase * BK]);
            async_load16(B + (size_t)(rB + rbase + lrow) * KDIM + kt + lcol,
                         &Bs[buf][rbase * BK]);
        }
    };

    int rA, rB, nA, nB;
    tileRows(0, rA, rB);
    stage(0, rA, rB, 0);
    __syncthreads();                      // drain prologue loads
    nA = rA; nB = rB;
    int buf = 0;

#pragma unroll 4
    for (int s = 0; s < NSTEPS; ++s) {
        // Phase 1: issue next K-step's loads (fly under compute).
        if (s + 1 < NSTEPS) {
            if (((s + 1) & 3) == 0) tileRows((s + 1) >> 2, nA, nB);
            stage(buf ^ 1, nA, nB, ((s + 1) & 3) * BK);
        }
        // Phase 2: compute current buffer.
#pragma unroll
        for (int kk = 0; kk < BK; kk += 32) {
            const int swz = kk ? swzhi : swzlo;
            v8bf a[4], b[2];
#pragma unroll
            for (int i = 0; i < 4; ++i)
                a[i] = *(const v8bf*)&As[buf][(wr * 64 + i * 16 + mrow) * BK + swz];
#pragma unroll
            for (int j = 0; j < 2; ++j)
                b[j] = *(const v8bf*)&Bs[buf][(wc * 32 + j * 16 + mrow) * BK + swz];
#pragma unroll
            for (int i = 0; i < 4; ++i)
#pragma unroll
                for (int j = 0; j < 2; ++j)
                    acc[i][j] = __builtin_amdgcn_mfma_f32_16x16x32_bf16(
                        a[i], b[j], acc[i][j], 0, 0, 0);
        }
        __syncthreads();  // reads of buf done + own next-loads drained
        buf ^= 1;
        // Tile boundary: fused epilogue (next tile's kt0 loads already landed;
        // stores drain asynchronously under the following compute steps).
        if ((s & 3) == 3) {
            const int m0 = rA + wr * 64;
            const int n0 = rB + wc * 32;
            float s2v[2];
#pragma unroll
            for (int j = 0; j < 2; ++j) s2v[j] = sq2[n0 + j * 16 + mrow];
#pragma unroll
            for (int i = 0; i < 4; ++i) {
                const int rbase = m0 + i * 16 + half * 4;
#pragma unroll
                for (int r = 0; r < 4; ++r) {
                    const float s1 = sq1[rbase + r];
                    float* op = out + (size_t)(rbase + r) * NROWS + n0 + mrow;
#pragma unroll
                    for (int j = 0; j < 2; ++j) {
                        const float d2 = s1 + s2v[j] - 2.0f * acc[i][j][r];
                        op[j * 16] = sqrtf(fmaxf(d2, 0.0f));
                        acc[i][j][r] = 0.f;   // re-arm accumulator
                    }
                }
            }
            rA = nA; rB = nB;
        }
    }
}

extern "C" void kernel_launch(void* const* d_in, const int* in_sizes, int n_in,
                              void* d_out, int out_size, void* d_ws, size_t ws_size,
                              hipStream_t stream) {
    const float* x1 = (const float*)d_in[0];
    const float* x2 = (const float*)d_in[1];
    float* out = (float*)d_out;

    // ws layout: A_bf16 (4 MiB) | B_bf16 (4 MiB) | sq1 (32 KiB) | sq2 (32 KiB)
    ushort* Ab = (ushort*)d_ws;
    ushort* Bb = Ab + (size_t)NROWS * KDIM;
    float* sq1 = (float*)(Bb + (size_t)NROWS * KDIM);
    float* sq2 = sq1 + NROWS;

    cvt_norm_kernel<<<NROWS / 2, 256, 0, stream>>>(x1, x2, Ab, Bb, sq1, sq2);

    // 512 persistent blocks (2/CU), 8 output tiles each.
    cdist_mfma_kernel<<<512, NTHREADS, 0, stream>>>(Ab, Bb, sq1, sq2, out);
}